// Round 1
// baseline (236.669 us; speedup 1.0000x reference)
//
#include <hip/hip_runtime.h>
#include <cstdint>
#include <cstddef>

// Problem constants
#define NUM_CODES 1024
#define DIM       256
#define NROWS     65536          // BATCH(8192) * NODE(8)
#define BM        128            // rows per block
#define LDS_STRIDE 264           // 256 + 8 pad (keeps 16B alignment, breaks bank conflicts)
#define OUT0_ELEMS 16777216      // 8192*8*256

typedef float v4f  __attribute__((ext_vector_type(4)));
typedef __bf16 v8bf __attribute__((ext_vector_type(8)));
typedef unsigned short v8us __attribute__((ext_vector_type(8)));

__device__ inline unsigned short f2bf_rne(float f) {
  union { float f; unsigned u; } c; c.f = f;
  unsigned u = c.u;
  unsigned r = (u + 0x7FFFu + ((u >> 16) & 1u)) >> 16;
  return (unsigned short)r;
}

// One block per code k (1024 blocks, 256 threads = one per d).
// Writes: e2[k] = ||e_k||^2 (fp32), eprep in MFMA-B fragment order (bf16 bits),
// and zeroes the loss accumulator slot.
__global__ __launch_bounds__(256) void vq_prep(const float* __restrict__ emb,
                                               unsigned short* __restrict__ eprep,
                                               float* __restrict__ e2,
                                               float* __restrict__ loss_slot) {
  const int k = blockIdx.x;
  const int d = threadIdx.x;
  float v = emb[k * DIM + d];

  float sq = v * v;
  #pragma unroll
  for (int off = 32; off; off >>= 1) sq += __shfl_down(sq, off);
  __shared__ float red[4];
  const int lane = threadIdx.x & 63, wv = threadIdx.x >> 6;
  if (lane == 0) red[wv] = sq;
  __syncthreads();
  if (threadIdx.x == 0) e2[k] = red[0] + red[1] + red[2] + red[3];
  if (blockIdx.x == 0 && threadIdx.x == 0) *loss_slot = 0.0f;

  // B-fragment layout for mfma_f32_16x16x32_bf16:
  // lane l holds B[kdim=(l>>4)*8+j][n=l&15]; tile = 16 codes (c16) x 32 d (kk)
  const int c16 = k >> 4;
  const int kk = d >> 5;
  const int quad = (d >> 3) & 3;
  const int j = d & 7;
  const int l = quad * 16 + (k & 15);
  eprep[(((c16 * 8 + kk) * 64) + l) * 8 + j] = f2bf_rne(v);
}

// 512 blocks x 256 threads. Block handles BM=128 rows x all 1024 codes.
__global__ __launch_bounds__(256, 2) void vq_main(const float* __restrict__ lat,
                                                  const float* __restrict__ emb,
                                                  const unsigned short* __restrict__ eprep,
                                                  const float* __restrict__ e2,
                                                  float* __restrict__ out,
                                                  float* __restrict__ loss_slot) {
  __shared__ __align__(16) unsigned short xlds[BM * LDS_STRIDE];
  __shared__ float rv[BM * 2];
  __shared__ int   ri[BM * 2];
  __shared__ int   fidx[BM];
  __shared__ float lred[4];

  const int tid = threadIdx.x;
  const int lane = tid & 63;
  const int w = tid >> 6;           // wave 0..3 (2x2 over rows x codes)
  const int lane15 = lane & 15;
  const int quad = lane >> 4;
  const size_t rowbase_g = (size_t)blockIdx.x * BM;

  // ---- stage X tile: fp32 global -> bf16 LDS (row-major, stride 264) ----
  const float4* latv = (const float4*)(lat + rowbase_g * DIM);
  #pragma unroll 4
  for (int i = 0; i < 32; ++i) {
    int g = i * 256 + tid;          // 8192 float4 per tile
    int row = g >> 6;               // 64 float4 per row
    int c4 = g & 63;
    float4 v = latv[g];
    ushort4 s;
    s.x = f2bf_rne(v.x); s.y = f2bf_rne(v.y);
    s.z = f2bf_rne(v.z); s.w = f2bf_rne(v.w);
    *(ushort4*)(&xlds[row * LDS_STRIDE + c4 * 4]) = s;
  }
  __syncthreads();

  // ---- MFMA score tiles + running per-lane argmin ----
  const int rowb = (w >> 1) * 64;   // wave's row offset inside block tile
  float minv[16];
  int   mini[16];
  #pragma unroll
  for (int s = 0; s < 16; ++s) { minv[s] = 3.4e38f; mini[s] = 0; }

  const v8us* __restrict__ bptr = (const v8us*)eprep;

  for (int ct = 0; ct < 8; ++ct) {          // 8 code tiles of 128
    v4f acc[4][4] = {};
    const int cb = ct * 128 + (w & 1) * 64; // wave's code base
    const int c16b = cb >> 4;

    #pragma unroll
    for (int kk = 0; kk < 8; ++kk) {        // D=256 in steps of 32
      v8bf a[4], b[4];
      #pragma unroll
      for (int mf = 0; mf < 4; ++mf) {
        const unsigned short* ap =
            &xlds[(rowb + mf * 16 + lane15) * LDS_STRIDE + kk * 32 + quad * 8];
        a[mf] = __builtin_bit_cast(v8bf, *(const v8us*)ap);
      }
      #pragma unroll
      for (int nf = 0; nf < 4; ++nf) {
        b[nf] = __builtin_bit_cast(v8bf, bptr[((c16b + nf) * 8 + kk) * 64 + lane]);
      }
      #pragma unroll
      for (int mf = 0; mf < 4; ++mf)
        #pragma unroll
        for (int nf = 0; nf < 4; ++nf)
          acc[mf][nf] = __builtin_amdgcn_mfma_f32_16x16x32_bf16(a[mf], b[nf], acc[mf][nf], 0, 0, 0);
    }

    // scores: s = ||e||^2 - 2*dot ; update running argmin
    // C/D layout: row = quad*4 + i, col = lane15
    #pragma unroll
    for (int nf = 0; nf < 4; ++nf) {
      const int code = cb + nf * 16 + lane15;
      const float e2v = e2[code];
      #pragma unroll
      for (int mf = 0; mf < 4; ++mf) {
        #pragma unroll
        for (int i = 0; i < 4; ++i) {
          float s = fmaf(-2.0f, acc[mf][nf][i], e2v);
          const int st = mf * 4 + i;
          if (s < minv[st]) { minv[st] = s; mini[st] = code; }
        }
      }
    }
  }

  // ---- argmin reduce across the 16 lanes sharing a quad ----
  #pragma unroll
  for (int s = 0; s < 16; ++s) {
    #pragma unroll
    for (int mask = 1; mask <= 8; mask <<= 1) {
      float ov = __shfl_xor(minv[s], mask);
      int   oi = __shfl_xor(mini[s], mask);
      if (ov < minv[s] || (ov == minv[s] && oi < mini[s])) { minv[s] = ov; mini[s] = oi; }
    }
  }
  if (lane15 == 0) {
    #pragma unroll
    for (int mf = 0; mf < 4; ++mf)
      #pragma unroll
      for (int i = 0; i < 4; ++i) {
        const int row = rowb + mf * 16 + quad * 4 + i;
        rv[row * 2 + (w & 1)] = minv[mf * 4 + i];
        ri[row * 2 + (w & 1)] = mini[mf * 4 + i];
      }
  }
  __syncthreads();
  if (tid < BM) {
    float v0 = rv[2 * tid], v1 = rv[2 * tid + 1];
    int   i0 = ri[2 * tid], i1 = ri[2 * tid + 1];
    fidx[tid] = (v1 < v0 || (v1 == v0 && i1 < i0)) ? i1 : i0;
  }
  __syncthreads();

  // ---- epilogue: gather codebook rows (fp32), write out, loss partial ----
  float partial = 0.0f;
  const float* latg = lat + rowbase_g * DIM;
  float* outg = out + rowbase_g * DIM;
  for (int r = 0; r < BM; ++r) {
    const int code = fidx[r];
    float ev = emb[code * DIM + tid];     // coalesced, L2-hot (1 MiB table)
    float lv = latg[r * DIM + tid];       // L2-hot (just staged)
    outg[r * DIM + tid] = ev;             // quantized_st == quantized numerically
    float d = lv - ev;
    partial = fmaf(d, d, partial);
  }
  #pragma unroll
  for (int off = 32; off; off >>= 1) partial += __shfl_down(partial, off);
  if (lane == 0) lred[w] = partial;
  __syncthreads();
  if (tid == 0)
    atomicAdd(loss_slot, (lred[0] + lred[1] + lred[2] + lred[3]) * (1.25f / 16777216.0f));
}

extern "C" void kernel_launch(void* const* d_in, const int* in_sizes, int n_in,
                              void* d_out, int out_size, void* d_ws, size_t ws_size,
                              hipStream_t stream) {
  const float* lat = (const float*)d_in[0];   // [8192, 2048] fp32
  const float* emb = (const float*)d_in[1];   // [1024, 256] fp32
  float* out = (float*)d_out;                 // [16777216] quantized_st + [1] vq_loss
  unsigned short* eprep = (unsigned short*)d_ws;                    // 512 KiB
  float* e2 = (float*)((char*)d_ws + NUM_CODES * DIM * sizeof(unsigned short));
  float* loss_slot = out + (size_t)OUT0_ELEMS;

  vq_prep<<<NUM_CODES, 256, 0, stream>>>(emb, eprep, e2, loss_slot);
  vq_main<<<NROWS / BM, 256, 0, stream>>>(lat, emb, eprep, e2, out, loss_slot);
}